// Round 3
// baseline (678.549 us; speedup 1.0000x reference)
//
#include <hip/hip_runtime.h>
#include <cstdint>
#include <cstddef>

// ---------------- numeric constants (fp64, 17 sig digits) ----------------
// psp IIR: d = exp(-1/tau), c = e/tau   (alpha kernel k(t) = c * t * d^t)
#define D_TAU1 0.36787944117144233   // exp(-1)
#define C_TAU1 2.7182818284590452    // e
#define D_TAU2 0.60653065971263342   // exp(-1/2)
#define C_TAU2 1.3591409142295226    // e/2
#define D_TAU4 0.77880078307140487   // exp(-1/4)
#define C_TAU4 0.67957045711476131   // e/4
// refractory: dr = exp(-1/tauRef), d32 = dr^32, cr = -2*theta*scaleRef*e/tauRef
#define DR1   0.36787944117144233
#define D32_1 1.2664165549094176e-14 // exp(-32)
#define CR1   -163.09690970754271    // -60e   (theta=30, tauRef=1)
#define DR2   0.60653065971263342
#define D32_2 1.1253517471925911e-7  // exp(-16)
#define CR2   -135.91409142295226    // -50e   (theta=50, tauRef=2)
#define DR3   0.77880078307140487
#define D32_3 3.3546262790251184e-4  // exp(-8)
#define CR3   -135.91409142295226    // -50e   (theta=100, tauRef=4)

// SLAYER spike scan with KREF=32 truncated refractory kernel: full alpha-IIR
// minus a 32-step-delayed alpha-IIR (exact cancellation outside the window).
struct Spike { double Arf, Brf, Ad, Bd; unsigned long long hist; };

__device__ __forceinline__ double spike_step(Spike& st, double u, int t,
                                             double theta, double dr,
                                             double d32, double cr) {
  const double R = cr * (st.Brf - d32 * (st.Bd + 32.0 * st.Ad));
  const double v = u + R;
  const bool fire = (v >= theta);
  const double s = fire ? 1.0 : 0.0;
  st.Brf = dr * (st.Brf + st.Arf);
  st.Arf = dr * st.Arf + s;
  const double sd = (t >= 32) ? (double)((st.hist >> (t - 32)) & 1ull) : 0.0;
  st.Bd = dr * (st.Bd + st.Ad);
  st.Ad = dr * st.Ad + sd;
  if (fire) st.hist |= (1ull << t);
  return s;
}

// ---------------- geometry ----------------
// B=8, T=64. Workspace (~42.4 MB):
//   P1p: (16 img, 64 t, 68, 68) fp64, pad 2 zero border   37.9 MB
//   S1 : (64 img = b*8+o, 4096 sites) uint64 spike masks   2 MB
//   S2 : (16 img = b*2+o, 16384 sites) uint64 masks        2 MB
//   IM : (16 img = b*2+c, 4096 sites) uint64 input masks   0.5 MB
#define P1_IS (68 * 68)

__global__ void k_zero_border(double* __restrict__ buf, int rows, int cols, int pad) {
  double* img = buf + (size_t)blockIdx.x * rows * cols;
  const int inner = rows - 2 * pad;
  const int cA = pad * cols;
  const int cC = inner * pad;
  const int total = 2 * cA + 2 * cC;
  for (int i = threadIdx.x; i < total; i += blockDim.x) {
    int r, c;
    if (i < cA)            { r = i / cols; c = i - r * cols; }
    else if (i < 2 * cA)   { int j = i - cA; int rr = j / cols; r = rows - pad + rr; c = j - rr * cols; }
    else if (i < 2*cA + cC){ int j = i - 2 * cA; int rr = j / pad; r = pad + rr; c = j - rr * pad; }
    else                   { int j = i - 2*cA - cC; int rr = j / pad; r = pad + rr; c = cols - pad + (j - rr * pad); }
    img[(size_t)r * cols + c] = 0.0;
  }
}

// K1: psp(spikeInput, tau=1) -> P1p interior; also input spike bitmasks -> IM.
__global__ __launch_bounds__(256) void k_psp1(const float* __restrict__ x,
                                              double* __restrict__ p1,
                                              unsigned long long* __restrict__ im) {
  const int idx = blockIdx.x * 256 + threadIdx.x;  // (bc,y,x), x fastest
  const int xw = idx & 63;
  const int yy = (idx >> 6) & 63;
  const int bc = idx >> 12;
  const float* xin = x + (size_t)idx * 64;         // T contiguous
  double* op = p1 + ((size_t)bc * 64) * P1_IS + (size_t)(yy + 2) * 68 + (xw + 2);
  double A = 0.0, Bv = 0.0;
  unsigned long long hist = 0ull;
  for (int t4 = 0; t4 < 16; ++t4) {
    const float4 v = reinterpret_cast<const float4*>(xin)[t4];
    const float f[4] = {v.x, v.y, v.z, v.w};
#pragma unroll
    for (int k = 0; k < 4; ++k) {
      if (f[k] != 0.0f) hist |= (1ull << (t4 * 4 + k));
      Bv = D_TAU1 * (Bv + A);
      A = D_TAU1 * A + (double)f[k];
      op[(size_t)(t4 * 4 + k) * P1_IS] = C_TAU1 * Bv;
    }
  }
  im[idx] = hist;
}

// K2: conv5x5(psp1) -> spike(theta=30,tauRef=1) -> S1 bitmask.
// Lane layout: lane = 8*o + xo. The 8 o-lanes share load addresses (coalescer
// dedupes -> 8x less L1 traffic); weights are per-lane (100 VGPR).
__global__ __launch_bounds__(256, 2) void k_conv1_spike(
    const double* __restrict__ p1, const float* __restrict__ w1f,
    unsigned long long* __restrict__ s1) {
  const int lane = threadIdx.x & 63;
  const int xo = lane & 7;
  const int o = lane >> 3;                 // 0..7
  const int wid = threadIdx.x >> 6;        // 0..3
  const int x = blockIdx.x * 8 + xo;       // 0..63
  const int y = blockIdx.y * 4 + wid;      // 0..63
  const int b = blockIdx.z;                // 0..7
  double w[50];
#pragma unroll
  for (int i = 0; i < 50; ++i) w[i] = (double)w1f[o * 50 + i];
  const double* b0 = p1 + ((size_t)(b * 2 + 0) * 64) * P1_IS + (size_t)y * 68 + x;
  const double* b1 = p1 + ((size_t)(b * 2 + 1) * 64) * P1_IS + (size_t)y * 68 + x;
  Spike st = {0.0, 0.0, 0.0, 0.0, 0ull};
  for (int t = 0; t < 64; ++t) {
    const double* q0 = b0 + (size_t)t * P1_IS;
    const double* q1 = b1 + (size_t)t * P1_IS;
    double u = 0.0;
#pragma unroll
    for (int ky = 0; ky < 5; ++ky) {
#pragma unroll
      for (int kx = 0; kx < 5; ++kx) {
        u = fma(w[ky * 5 + kx],      q0[(size_t)ky * 68 + kx], u);
        u = fma(w[25 + ky * 5 + kx], q1[(size_t)ky * 68 + kx], u);
      }
    }
    (void)spike_step(st, u, t, 30.0, DR1, D32_1, CR1);
  }
  s1[(size_t)(b * 8 + o) * 4096 + y * 64 + x] = st.hist;
}

// K3: deconv2x2-s2(psp(s1,tau=2)) -> spike -> S2. Both o's per thread:
// the 8 input-channel psp2 IIRs are shared across o.
__global__ __launch_bounds__(256, 2) void k_deconv_spike(
    const unsigned long long* __restrict__ s1, const float* __restrict__ w2f,
    unsigned long long* __restrict__ s2) {
  const int X = threadIdx.x;                       // 0..127
  const int Y = blockIdx.x * 2 + threadIdx.y;      // 0..127
  const int b = blockIdx.z;                        // 0..7
  const int xi = X >> 1, jj = X & 1, yi = Y >> 1, ii = Y & 1;
  double wA[8], wB[8];
  unsigned long long m[8];
#pragma unroll
  for (int c = 0; c < 8; ++c) {
    wA[c] = (double)w2f[((c * 2 + 0) * 2 + ii) * 2 + jj] * C_TAU2;
    wB[c] = (double)w2f[((c * 2 + 1) * 2 + ii) * 2 + jj] * C_TAU2;
    m[c] = s1[(size_t)(b * 8 + c) * 4096 + yi * 64 + xi];
  }
  double A[8], Bv[8];
#pragma unroll
  for (int c = 0; c < 8; ++c) { A[c] = 0.0; Bv[c] = 0.0; }
  Spike st0 = {0.0, 0.0, 0.0, 0.0, 0ull};
  Spike st1 = {0.0, 0.0, 0.0, 0.0, 0ull};
  for (int t = 0; t < 64; ++t) {
    double u0 = 0.0, u1 = 0.0;
#pragma unroll
    for (int c = 0; c < 8; ++c) {
      Bv[c] = D_TAU2 * (Bv[c] + A[c]);
      A[c] = D_TAU2 * A[c] + (double)((m[c] >> t) & 1ull);
      u0 = fma(wA[c], Bv[c], u0);
      u1 = fma(wB[c], Bv[c], u1);
    }
    (void)spike_step(st0, u0, t, 50.0, DR2, D32_2, CR2);
    (void)spike_step(st1, u1, t, 50.0, DR2, D32_2, CR2);
  }
  s2[(size_t)(b * 2 + 0) * 16384 + Y * 128 + X] = st0.hist;
  s2[(size_t)(b * 2 + 1) * 16384 + Y * 128 + X] = st1.hist;
}

// K4: conv3x3(psp(s2,tau=4)) + psp(bilinear(input),tau=1) skip
//     -> spike(theta=100,tauRef=4) -> d_out. Both o's per thread: the 18
//     psp3 IIRs are shared; skip uses input masks (psp/bilinear commute).
__global__ __launch_bounds__(256, 2) void k_conv3_spike_out(
    const unsigned long long* __restrict__ s2, const float* __restrict__ w3f,
    const unsigned long long* __restrict__ im, float* __restrict__ out) {
  const int X = threadIdx.x;                       // 0..127
  const int Y = blockIdx.x * 2 + threadIdx.y;      // 0..127
  const int b = blockIdx.z;                        // 0..7
  double wA[18], wB[18];
#pragma unroll
  for (int i = 0; i < 18; ++i) {
    wA[i] = (double)w3f[i]      * C_TAU4;
    wB[i] = (double)w3f[18 + i] * C_TAU4;
  }
  unsigned long long m[18];
#pragma unroll
  for (int cc = 0; cc < 2; ++cc)
#pragma unroll
    for (int ky = 0; ky < 3; ++ky)
#pragma unroll
      for (int kx = 0; kx < 3; ++kx) {
        const int yn = Y - 1 + ky, xn = X - 1 + kx;
        const bool ok = (yn >= 0) & (yn < 128) & (xn >= 0) & (xn < 128);
        m[cc * 9 + ky * 3 + kx] = ok ?
          s2[(size_t)(b * 2 + cc) * 16384 + yn * 128 + xn] : 0ull;
      }
  double A[18], Bv[18];
#pragma unroll
  for (int i = 0; i < 18; ++i) { A[i] = 0.0; Bv[i] = 0.0; }
  // bilinear 2x taps (half-pixel, clamped) applied to INPUT spike masks
  const int y0 = (Y - 1) >> 1;
  const int x0 = (X - 1) >> 1;
  const double wy1 = (Y & 1) ? 0.25 : 0.75, wy0 = 1.0 - wy1;
  const double wx1 = (X & 1) ? 0.25 : 0.75, wx0 = 1.0 - wx1;
  const int iy0 = max(y0, 0), iy1 = min(y0 + 1, 63);
  const int ix0 = max(x0, 0), ix1 = min(x0 + 1, 63);
  const double w00 = wy0 * wx0, w01 = wy0 * wx1, w10 = wy1 * wx0, w11 = wy1 * wx1;
  unsigned long long sk0[4], sk1[4];
#pragma unroll
  for (int o = 0; o < 2; ++o) {
    const unsigned long long* q = im + (size_t)(b * 2 + o) * 4096;
    unsigned long long* dst = o ? sk1 : sk0;
    dst[0] = q[iy0 * 64 + ix0]; dst[1] = q[iy0 * 64 + ix1];
    dst[2] = q[iy1 * 64 + ix0]; dst[3] = q[iy1 * 64 + ix1];
  }
  double As0 = 0.0, Bs0 = 0.0, As1 = 0.0, Bs1 = 0.0;
  Spike st0 = {0.0, 0.0, 0.0, 0.0, 0ull};
  Spike st1 = {0.0, 0.0, 0.0, 0.0, 0ull};
  for (int t = 0; t < 64; ++t) {
    double u0 = 0.0, u1 = 0.0;
#pragma unroll
    for (int i = 0; i < 18; ++i) {
      Bv[i] = D_TAU4 * (Bv[i] + A[i]);
      A[i] = D_TAU4 * A[i] + (double)((m[i] >> t) & 1ull);
      u0 = fma(wA[i], Bv[i], u0);
      u1 = fma(wB[i], Bv[i], u1);
    }
    const double d0 = w00 * (double)((sk0[0] >> t) & 1ull) + w01 * (double)((sk0[1] >> t) & 1ull)
                    + w10 * (double)((sk0[2] >> t) & 1ull) + w11 * (double)((sk0[3] >> t) & 1ull);
    const double d1 = w00 * (double)((sk1[0] >> t) & 1ull) + w01 * (double)((sk1[1] >> t) & 1ull)
                    + w10 * (double)((sk1[2] >> t) & 1ull) + w11 * (double)((sk1[3] >> t) & 1ull);
    Bs0 = D_TAU1 * (Bs0 + As0); As0 = D_TAU1 * As0 + d0;
    Bs1 = D_TAU1 * (Bs1 + As1); As1 = D_TAU1 * As1 + d1;
    u0 = fma(C_TAU1, Bs0, u0);
    u1 = fma(C_TAU1, Bs1, u1);
    (void)spike_step(st0, u0, t, 100.0, DR3, D32_3, CR3);
    (void)spike_step(st1, u1, t, 100.0, DR3, D32_3, CR3);
  }
#pragma unroll
  for (int o = 0; o < 2; ++o) {
    const unsigned long long h = o ? st1.hist : st0.hist;
    float* op = out + (((size_t)(b * 2 + o) * 128 + Y) * 128 + X) * 64;
#pragma unroll
    for (int t4 = 0; t4 < 16; ++t4) {
      float4 v;
      v.x = ((h >> (t4 * 4 + 0)) & 1ull) ? 1.0f : 0.0f;
      v.y = ((h >> (t4 * 4 + 1)) & 1ull) ? 1.0f : 0.0f;
      v.z = ((h >> (t4 * 4 + 2)) & 1ull) ? 1.0f : 0.0f;
      v.w = ((h >> (t4 * 4 + 3)) & 1ull) ? 1.0f : 0.0f;
      reinterpret_cast<float4*>(op)[t4] = v;
    }
  }
}

extern "C" void kernel_launch(void* const* d_in, const int* in_sizes, int n_in,
                              void* d_out, int out_size, void* d_ws, size_t ws_size,
                              hipStream_t stream) {
  const float* spikeIn = (const float*)d_in[0];   // (8,2,64,64,64) fp32
  const float* w1 = (const float*)d_in[1];        // (8,2,5,5)
  const float* w2 = (const float*)d_in[2];        // (8,2,2,2) = (in,out,i,j)
  const float* w3 = (const float*)d_in[3];        // (2,2,3,3)
  float* out = (float*)d_out;                     // (8,2,128,128,64) fp32

  double* P1p = (double*)d_ws;                                   // 37.9 MB
  unsigned long long* S1 = (unsigned long long*)(P1p + (size_t)16 * 64 * P1_IS);
  unsigned long long* S2 = S1 + (size_t)64 * 4096;               // +2 MB
  unsigned long long* IM = S2 + (size_t)16 * 16384;              // +2 MB, +0.5 MB

  k_zero_border<<<dim3(16 * 64), dim3(128), 0, stream>>>(P1p, 68, 68, 2);
  k_psp1<<<dim3(256), dim3(256), 0, stream>>>(spikeIn, P1p, IM);
  k_conv1_spike<<<dim3(8, 16, 8), dim3(256), 0, stream>>>(P1p, w1, S1);
  k_deconv_spike<<<dim3(64, 1, 8), dim3(128, 2), 0, stream>>>(S1, w2, S2);
  k_conv3_spike_out<<<dim3(64, 1, 8), dim3(128, 2), 0, stream>>>(S2, w3, IM, out);
}

// Round 4
// 297.418 us; speedup vs baseline: 2.2815x; 2.2815x over previous
//
#include <hip/hip_runtime.h>
#include <cstdint>
#include <cstddef>

// ---------------- numeric constants (fp64, 17 sig digits) ----------------
// psp IIR: d = exp(-1/tau), c = e/tau   (alpha kernel k(t) = c * t * d^t)
#define D_TAU1 0.36787944117144233   // exp(-1)
#define C_TAU1 2.7182818284590452    // e
#define D_TAU2 0.60653065971263342   // exp(-1/2)
#define C_TAU2 1.3591409142295226    // e/2
#define D_TAU4 0.77880078307140487   // exp(-1/4)
#define C_TAU4 0.67957045711476131   // e/4
// refractory: dr = exp(-1/tauRef), d32 = dr^32, cr = -2*theta*scaleRef*e/tauRef
#define DR1   0.36787944117144233
#define D32_1 1.2664165549094176e-14 // exp(-32)
#define CR1   -163.09690970754271    // -60e   (theta=30, tauRef=1)
#define DR2   0.60653065971263342
#define D32_2 1.1253517471925911e-7  // exp(-16)
#define CR2   -135.91409142295226    // -50e   (theta=50, tauRef=2)
#define DR3   0.77880078307140487
#define D32_3 3.3546262790251184e-4  // exp(-8)
#define CR3   -135.91409142295226    // -50e   (theta=100, tauRef=4)

// SLAYER spike scan with KREF=32 truncated refractory kernel: full alpha-IIR
// minus a 32-step-delayed alpha-IIR (exact cancellation outside the window).
struct Spike { double Arf, Brf, Ad, Bd; unsigned long long hist; };

__device__ __forceinline__ double spike_step(Spike& st, double u, int t,
                                             double theta, double dr,
                                             double d32, double cr) {
  const double R = cr * (st.Brf - d32 * (st.Bd + 32.0 * st.Ad));
  const double v = u + R;
  const bool fire = (v >= theta);
  const double s = fire ? 1.0 : 0.0;
  st.Brf = dr * (st.Brf + st.Arf);
  st.Arf = dr * st.Arf + s;
  const double sd = (t >= 32) ? (double)((st.hist >> (t - 32)) & 1ull) : 0.0;
  st.Bd = dr * (st.Bd + st.Ad);
  st.Ad = dr * st.Ad + sd;
  if (fire) st.hist |= (1ull << t);
  return s;
}

// ---------------- geometry ----------------
// B=8, T=64. Workspace (~42.4 MB):
//   P1p: (16 img, 64 t, 68, 68) fp64, pad 2 zero border   37.9 MB
//   S1 : (64 img = b*8+o, 4096 sites) uint64 spike masks   2 MB
//   S2 : (16 img = b*2+o, 16384 sites) uint64 masks        2 MB
//   IM : (16 img = b*2+c, 4096 sites) uint64 input masks   0.5 MB
#define P1_IS (68 * 68)

__global__ void k_zero_border(double* __restrict__ buf, int rows, int cols, int pad) {
  double* img = buf + (size_t)blockIdx.x * rows * cols;
  const int inner = rows - 2 * pad;
  const int cA = pad * cols;
  const int cC = inner * pad;
  const int total = 2 * cA + 2 * cC;
  for (int i = threadIdx.x; i < total; i += blockDim.x) {
    int r, c;
    if (i < cA)            { r = i / cols; c = i - r * cols; }
    else if (i < 2 * cA)   { int j = i - cA; int rr = j / cols; r = rows - pad + rr; c = j - rr * cols; }
    else if (i < 2*cA + cC){ int j = i - 2 * cA; int rr = j / pad; r = pad + rr; c = j - rr * pad; }
    else                   { int j = i - 2*cA - cC; int rr = j / pad; r = pad + rr; c = cols - pad + (j - rr * pad); }
    img[(size_t)r * cols + c] = 0.0;
  }
}

// K1: psp(spikeInput, tau=1) -> P1p interior; also input spike bitmasks -> IM.
__global__ __launch_bounds__(256) void k_psp1(const float* __restrict__ x,
                                              double* __restrict__ p1,
                                              unsigned long long* __restrict__ im) {
  const int idx = blockIdx.x * 256 + threadIdx.x;  // (bc,y,x), x fastest
  const int xw = idx & 63;
  const int yy = (idx >> 6) & 63;
  const int bc = idx >> 12;
  const float* xin = x + (size_t)idx * 64;         // T contiguous
  double* op = p1 + ((size_t)bc * 64) * P1_IS + (size_t)(yy + 2) * 68 + (xw + 2);
  double A = 0.0, Bv = 0.0;
  unsigned long long hist = 0ull;
  for (int t4 = 0; t4 < 16; ++t4) {
    const float4 v = reinterpret_cast<const float4*>(xin)[t4];
    const float f[4] = {v.x, v.y, v.z, v.w};
#pragma unroll
    for (int k = 0; k < 4; ++k) {
      if (f[k] != 0.0f) hist |= (1ull << (t4 * 4 + k));
      Bv = D_TAU1 * (Bv + A);
      A = D_TAU1 * A + (double)f[k];
      op[(size_t)(t4 * 4 + k) * P1_IS] = C_TAU1 * Bv;
    }
  }
  im[idx] = hist;
}

// K2: conv5x5(psp1) -> spike(theta=30,tauRef=1) -> S1 bitmask.
// o is block-uniform (weights wave-uniform; R3 showed per-lane weights spill).
// Each thread computes a 2x2 output tile: 6x6x2 window as 36 double2 loads
// (16B, lane-consecutive) = 576 B/thread/t; 200 FMA/thread/t -> FMA-bound.
__global__ __launch_bounds__(256) void k_conv1_spike(
    const double* __restrict__ p1, const float* __restrict__ w1f,
    unsigned long long* __restrict__ s1) {
  const int tid = threadIdx.x;
  const int xo2 = tid & 31;                 // x-pair index
  const int yo2 = tid >> 5;                 // y-pair within block (0..7)
  const int x = xo2 * 2;                    // 0..62
  const int y = blockIdx.x * 16 + yo2 * 2;  // 0..62
  const int o = blockIdx.y;                 // 0..7
  const int b = blockIdx.z;                 // 0..7
  double w[50];
#pragma unroll
  for (int i = 0; i < 50; ++i) w[i] = (double)w1f[o * 50 + i];
  const double* base0 = p1 + ((size_t)(b * 2 + 0) * 64) * P1_IS + (size_t)y * 68 + x;
  const double* base1 = p1 + ((size_t)(b * 2 + 1) * 64) * P1_IS + (size_t)y * 68 + x;
  Spike s00 = {0,0,0,0,0ull}, s01 = {0,0,0,0,0ull};
  Spike s10 = {0,0,0,0,0ull}, s11 = {0,0,0,0,0ull};
  for (int t = 0; t < 64; ++t) {
    double u00 = 0.0, u01 = 0.0, u10 = 0.0, u11 = 0.0;
#pragma unroll
    for (int ch = 0; ch < 2; ++ch) {
      const double* q = (ch ? base1 : base0) + (size_t)t * P1_IS;
      const double* wc = w + ch * 25;
#pragma unroll
      for (int r = 0; r < 6; ++r) {
        const double2 a0 = reinterpret_cast<const double2*>(q + (size_t)r * 68)[0];
        const double2 a1 = reinterpret_cast<const double2*>(q + (size_t)r * 68)[1];
        const double2 a2 = reinterpret_cast<const double2*>(q + (size_t)r * 68)[2];
        const double v0 = a0.x, v1 = a0.y, v2 = a1.x, v3 = a1.y, v4 = a2.x, v5 = a2.y;
        if (r <= 4) {  // dy = 0 uses ky = r
          const double* wr = wc + r * 5;
          u00 = fma(wr[0], v0, u00); u00 = fma(wr[1], v1, u00);
          u00 = fma(wr[2], v2, u00); u00 = fma(wr[3], v3, u00);
          u00 = fma(wr[4], v4, u00);
          u01 = fma(wr[0], v1, u01); u01 = fma(wr[1], v2, u01);
          u01 = fma(wr[2], v3, u01); u01 = fma(wr[3], v4, u01);
          u01 = fma(wr[4], v5, u01);
        }
        if (r >= 1) {  // dy = 1 uses ky = r-1
          const double* wr = wc + (r - 1) * 5;
          u10 = fma(wr[0], v0, u10); u10 = fma(wr[1], v1, u10);
          u10 = fma(wr[2], v2, u10); u10 = fma(wr[3], v3, u10);
          u10 = fma(wr[4], v4, u10);
          u11 = fma(wr[0], v1, u11); u11 = fma(wr[1], v2, u11);
          u11 = fma(wr[2], v3, u11); u11 = fma(wr[3], v4, u11);
          u11 = fma(wr[4], v5, u11);
        }
      }
    }
    (void)spike_step(s00, u00, t, 30.0, DR1, D32_1, CR1);
    (void)spike_step(s01, u01, t, 30.0, DR1, D32_1, CR1);
    (void)spike_step(s10, u10, t, 30.0, DR1, D32_1, CR1);
    (void)spike_step(s11, u11, t, 30.0, DR1, D32_1, CR1);
  }
  unsigned long long* sp = s1 + (size_t)(b * 8 + o) * 4096;
  sp[(y + 0) * 64 + x]     = s00.hist;
  sp[(y + 0) * 64 + x + 1] = s01.hist;
  sp[(y + 1) * 64 + x]     = s10.hist;
  sp[(y + 1) * 64 + x + 1] = s11.hist;
}

// K3: deconv2x2-s2(psp(s1,tau=2)) -> spike -> S2. Both o's per thread:
// the 8 input-channel psp2 IIRs are shared across o.
__global__ __launch_bounds__(256, 2) void k_deconv_spike(
    const unsigned long long* __restrict__ s1, const float* __restrict__ w2f,
    unsigned long long* __restrict__ s2) {
  const int X = threadIdx.x;                       // 0..127
  const int Y = blockIdx.x * 2 + threadIdx.y;      // 0..127
  const int b = blockIdx.z;                        // 0..7
  const int xi = X >> 1, jj = X & 1, yi = Y >> 1, ii = Y & 1;
  double wA[8], wB[8];
  unsigned long long m[8];
#pragma unroll
  for (int c = 0; c < 8; ++c) {
    wA[c] = (double)w2f[((c * 2 + 0) * 2 + ii) * 2 + jj] * C_TAU2;
    wB[c] = (double)w2f[((c * 2 + 1) * 2 + ii) * 2 + jj] * C_TAU2;
    m[c] = s1[(size_t)(b * 8 + c) * 4096 + yi * 64 + xi];
  }
  double A[8], Bv[8];
#pragma unroll
  for (int c = 0; c < 8; ++c) { A[c] = 0.0; Bv[c] = 0.0; }
  Spike st0 = {0.0, 0.0, 0.0, 0.0, 0ull};
  Spike st1 = {0.0, 0.0, 0.0, 0.0, 0ull};
  for (int t = 0; t < 64; ++t) {
    double u0 = 0.0, u1 = 0.0;
#pragma unroll
    for (int c = 0; c < 8; ++c) {
      Bv[c] = D_TAU2 * (Bv[c] + A[c]);
      A[c] = D_TAU2 * A[c] + (double)((m[c] >> t) & 1ull);
      u0 = fma(wA[c], Bv[c], u0);
      u1 = fma(wB[c], Bv[c], u1);
    }
    (void)spike_step(st0, u0, t, 50.0, DR2, D32_2, CR2);
    (void)spike_step(st1, u1, t, 50.0, DR2, D32_2, CR2);
  }
  s2[(size_t)(b * 2 + 0) * 16384 + Y * 128 + X] = st0.hist;
  s2[(size_t)(b * 2 + 1) * 16384 + Y * 128 + X] = st1.hist;
}

// K4: conv3x3(psp(s2,tau=4)) + psp(bilinear(input),tau=1) skip
//     -> spike(theta=100,tauRef=4) -> d_out. Both o's per thread: the 18
//     psp3 IIRs are shared; skip uses input masks (psp/bilinear commute).
__global__ __launch_bounds__(256, 2) void k_conv3_spike_out(
    const unsigned long long* __restrict__ s2, const float* __restrict__ w3f,
    const unsigned long long* __restrict__ im, float* __restrict__ out) {
  const int X = threadIdx.x;                       // 0..127
  const int Y = blockIdx.x * 2 + threadIdx.y;      // 0..127
  const int b = blockIdx.z;                        // 0..7
  double wA[18], wB[18];
#pragma unroll
  for (int i = 0; i < 18; ++i) {
    wA[i] = (double)w3f[i]      * C_TAU4;
    wB[i] = (double)w3f[18 + i] * C_TAU4;
  }
  unsigned long long m[18];
#pragma unroll
  for (int cc = 0; cc < 2; ++cc)
#pragma unroll
    for (int ky = 0; ky < 3; ++ky)
#pragma unroll
      for (int kx = 0; kx < 3; ++kx) {
        const int yn = Y - 1 + ky, xn = X - 1 + kx;
        const bool ok = (yn >= 0) & (yn < 128) & (xn >= 0) & (xn < 128);
        m[cc * 9 + ky * 3 + kx] = ok ?
          s2[(size_t)(b * 2 + cc) * 16384 + yn * 128 + xn] : 0ull;
      }
  double A[18], Bv[18];
#pragma unroll
  for (int i = 0; i < 18; ++i) { A[i] = 0.0; Bv[i] = 0.0; }
  // bilinear 2x taps (half-pixel, clamped) applied to INPUT spike masks
  const int y0 = (Y - 1) >> 1;
  const int x0 = (X - 1) >> 1;
  const double wy1 = (Y & 1) ? 0.25 : 0.75, wy0 = 1.0 - wy1;
  const double wx1 = (X & 1) ? 0.25 : 0.75, wx0 = 1.0 - wx1;
  const int iy0 = max(y0, 0), iy1 = min(y0 + 1, 63);
  const int ix0 = max(x0, 0), ix1 = min(x0 + 1, 63);
  const double w00 = wy0 * wx0, w01 = wy0 * wx1, w10 = wy1 * wx0, w11 = wy1 * wx1;
  unsigned long long sk0[4], sk1[4];
#pragma unroll
  for (int o = 0; o < 2; ++o) {
    const unsigned long long* q = im + (size_t)(b * 2 + o) * 4096;
    unsigned long long* dst = o ? sk1 : sk0;
    dst[0] = q[iy0 * 64 + ix0]; dst[1] = q[iy0 * 64 + ix1];
    dst[2] = q[iy1 * 64 + ix0]; dst[3] = q[iy1 * 64 + ix1];
  }
  double As0 = 0.0, Bs0 = 0.0, As1 = 0.0, Bs1 = 0.0;
  Spike st0 = {0.0, 0.0, 0.0, 0.0, 0ull};
  Spike st1 = {0.0, 0.0, 0.0, 0.0, 0ull};
  for (int t = 0; t < 64; ++t) {
    double u0 = 0.0, u1 = 0.0;
#pragma unroll
    for (int i = 0; i < 18; ++i) {
      Bv[i] = D_TAU4 * (Bv[i] + A[i]);
      A[i] = D_TAU4 * A[i] + (double)((m[i] >> t) & 1ull);
      u0 = fma(wA[i], Bv[i], u0);
      u1 = fma(wB[i], Bv[i], u1);
    }
    const double d0 = w00 * (double)((sk0[0] >> t) & 1ull) + w01 * (double)((sk0[1] >> t) & 1ull)
                    + w10 * (double)((sk0[2] >> t) & 1ull) + w11 * (double)((sk0[3] >> t) & 1ull);
    const double d1 = w00 * (double)((sk1[0] >> t) & 1ull) + w01 * (double)((sk1[1] >> t) & 1ull)
                    + w10 * (double)((sk1[2] >> t) & 1ull) + w11 * (double)((sk1[3] >> t) & 1ull);
    Bs0 = D_TAU1 * (Bs0 + As0); As0 = D_TAU1 * As0 + d0;
    Bs1 = D_TAU1 * (Bs1 + As1); As1 = D_TAU1 * As1 + d1;
    u0 = fma(C_TAU1, Bs0, u0);
    u1 = fma(C_TAU1, Bs1, u1);
    (void)spike_step(st0, u0, t, 100.0, DR3, D32_3, CR3);
    (void)spike_step(st1, u1, t, 100.0, DR3, D32_3, CR3);
  }
#pragma unroll
  for (int o = 0; o < 2; ++o) {
    const unsigned long long h = o ? st1.hist : st0.hist;
    float* op = out + (((size_t)(b * 2 + o) * 128 + Y) * 128 + X) * 64;
#pragma unroll
    for (int t4 = 0; t4 < 16; ++t4) {
      float4 v;
      v.x = ((h >> (t4 * 4 + 0)) & 1ull) ? 1.0f : 0.0f;
      v.y = ((h >> (t4 * 4 + 1)) & 1ull) ? 1.0f : 0.0f;
      v.z = ((h >> (t4 * 4 + 2)) & 1ull) ? 1.0f : 0.0f;
      v.w = ((h >> (t4 * 4 + 3)) & 1ull) ? 1.0f : 0.0f;
      reinterpret_cast<float4*>(op)[t4] = v;
    }
  }
}

extern "C" void kernel_launch(void* const* d_in, const int* in_sizes, int n_in,
                              void* d_out, int out_size, void* d_ws, size_t ws_size,
                              hipStream_t stream) {
  const float* spikeIn = (const float*)d_in[0];   // (8,2,64,64,64) fp32
  const float* w1 = (const float*)d_in[1];        // (8,2,5,5)
  const float* w2 = (const float*)d_in[2];        // (8,2,2,2) = (in,out,i,j)
  const float* w3 = (const float*)d_in[3];        // (2,2,3,3)
  float* out = (float*)d_out;                     // (8,2,128,128,64) fp32

  double* P1p = (double*)d_ws;                                   // 37.9 MB
  unsigned long long* S1 = (unsigned long long*)(P1p + (size_t)16 * 64 * P1_IS);
  unsigned long long* S2 = S1 + (size_t)64 * 4096;               // +2 MB
  unsigned long long* IM = S2 + (size_t)16 * 16384;              // +2 MB, +0.5 MB

  k_zero_border<<<dim3(16 * 64), dim3(128), 0, stream>>>(P1p, 68, 68, 2);
  k_psp1<<<dim3(256), dim3(256), 0, stream>>>(spikeIn, P1p, IM);
  k_conv1_spike<<<dim3(4, 8, 8), dim3(256), 0, stream>>>(P1p, w1, S1);
  k_deconv_spike<<<dim3(64, 1, 8), dim3(128, 2), 0, stream>>>(S1, w2, S2);
  k_conv3_spike_out<<<dim3(64, 1, 8), dim3(128, 2), 0, stream>>>(S2, w3, IM, out);
}

// Round 5
// 241.041 us; speedup vs baseline: 2.8151x; 1.2339x over previous
//
#include <hip/hip_runtime.h>
#include <cstdint>
#include <cstddef>

// ---------------- numeric constants (fp64, 17 sig digits) ----------------
// psp IIR: d = exp(-1/tau), c = e/tau   (alpha kernel k(t) = c * t * d^t)
#define D_TAU1 0.36787944117144233   // exp(-1)
#define C_TAU1 2.7182818284590452    // e
#define D_TAU2 0.60653065971263342   // exp(-1/2)
#define C_TAU2 1.3591409142295226    // e/2
#define D_TAU4 0.77880078307140487   // exp(-1/4)
#define C_TAU4 0.67957045711476131   // e/4
// refractory: dr = exp(-1/tauRef), d32 = dr^32, cr = -2*theta*scaleRef*e/tauRef
#define DR1   0.36787944117144233
#define D32_1 1.2664165549094176e-14 // exp(-32)
#define CR1   -163.09690970754271    // -60e   (theta=30, tauRef=1)
#define DR2   0.60653065971263342
#define D32_2 1.1253517471925911e-7  // exp(-16)
#define CR2   -135.91409142295226    // -50e   (theta=50, tauRef=2)
#define DR3   0.77880078307140487
#define D32_3 3.3546262790251184e-4  // exp(-8)
#define CR3   -135.91409142295226    // -50e   (theta=100, tauRef=4)

// SLAYER spike scan with KREF=32 truncated refractory kernel: full alpha-IIR
// minus a 32-step-delayed alpha-IIR (exact cancellation outside the window).
struct Spike { double Arf, Brf, Ad, Bd; unsigned long long hist; };

__device__ __forceinline__ double spike_step(Spike& st, double u, int t,
                                             double theta, double dr,
                                             double d32, double cr) {
  const double R = cr * (st.Brf - d32 * (st.Bd + 32.0 * st.Ad));
  const double v = u + R;
  const bool fire = (v >= theta);
  const double s = fire ? 1.0 : 0.0;
  st.Brf = dr * (st.Brf + st.Arf);
  st.Arf = dr * st.Arf + s;
  const double sd = (t >= 32) ? (double)((st.hist >> (t - 32)) & 1ull) : 0.0;
  st.Bd = dr * (st.Bd + st.Ad);
  st.Ad = dr * st.Ad + sd;
  if (fire) st.hist |= (1ull << t);
  return s;
}

// (m >> tt) & 1 as double; tt in [0,32) -> v_bfe_u32 + v_cvt_f64_u32
__device__ __forceinline__ double bitd(unsigned m, int tt) {
  return (double)((m >> tt) & 1u);
}

// ---------------- geometry ----------------
// B=8, T=64. Workspace (4.5 MB):
//   IM : (16 img = b*2+c, 64*64 sites)  uint64 input spike masks  0.5 MB
//   S1 : (64 img = b*8+o, 64*64 sites)  uint64 layer-1 masks      2 MB
//   S2 : (16 img = b*2+o, 128*128)      uint64 layer-2 masks      2 MB
// All convs use linearity: conv(psp(x)) == psp(conv(x)); drive = sum w_i*bit_i,
// single alpha-IIR per output channel, C-scale folded into the weights.

// K1: input spikes -> bitmasks.
__global__ __launch_bounds__(256) void k_masks(const float* __restrict__ x,
                                               unsigned long long* __restrict__ im) {
  const int idx = blockIdx.x * 256 + threadIdx.x;  // (bc,y,x), x fastest
  const float* xin = x + (size_t)idx * 64;
  unsigned long long hist = 0ull;
  for (int t4 = 0; t4 < 16; ++t4) {
    const float4 v = reinterpret_cast<const float4*>(xin)[t4];
    if (v.x != 0.0f) hist |= 1ull << (t4 * 4 + 0);
    if (v.y != 0.0f) hist |= 1ull << (t4 * 4 + 1);
    if (v.z != 0.0f) hist |= 1ull << (t4 * 4 + 2);
    if (v.w != 0.0f) hist |= 1ull << (t4 * 4 + 3);
  }
  im[idx] = hist;
}

// ---- K2: spike1 = spike(psp1(conv5x5(input))), x-pair tile, o in grid ----
__device__ __forceinline__ void k2_half(const unsigned (&mm)[2][5][6],
    const double (&w)[50], int tbase,
    double& A0, double& B0, double& A1, double& B1, Spike& st0, Spike& st1) {
  for (int tt = 0; tt < 32; ++tt) {
    const int t = tbase + tt;
    double d0 = 0.0, d1 = 0.0;
#pragma unroll
    for (int ch = 0; ch < 2; ++ch)
#pragma unroll
      for (int r = 0; r < 5; ++r) {
        double bb[6];
#pragma unroll
        for (int c = 0; c < 6; ++c) bb[c] = bitd(mm[ch][r][c], tt);
        const double* wr = &w[ch * 25 + r * 5];
#pragma unroll
        for (int c = 0; c < 5; ++c) {
          d0 = fma(wr[c], bb[c], d0);
          d1 = fma(wr[c], bb[c + 1], d1);
        }
      }
    B0 = D_TAU1 * (B0 + A0); A0 = D_TAU1 * A0 + d0;
    B1 = D_TAU1 * (B1 + A1); A1 = D_TAU1 * A1 + d1;
    (void)spike_step(st0, B0, t, 30.0, DR1, D32_1, CR1);
    (void)spike_step(st1, B1, t, 30.0, DR1, D32_1, CR1);
  }
}

__global__ __launch_bounds__(256, 2) void k_conv1_spike(
    const unsigned long long* __restrict__ im, const float* __restrict__ w1f,
    unsigned long long* __restrict__ s1) {
  const int tid = threadIdx.x;
  const int xo = tid & 31;                  // x-pair
  const int yo = tid >> 5;                  // 0..7
  const int x = xo * 2;                     // 0..62
  const int y = blockIdx.x * 8 + yo;        // 0..63
  const int o = blockIdx.y;                 // 0..7
  const int b = blockIdx.z;                 // 0..7
  double w[50];
#pragma unroll
  for (int i = 0; i < 50; ++i) w[i] = (double)w1f[o * 50 + i] * C_TAU1;
  const unsigned* im32 = (const unsigned*)im;
  double A0 = 0.0, B0 = 0.0, A1 = 0.0, B1 = 0.0;
  Spike st0 = {0, 0, 0, 0, 0ull}, st1 = {0, 0, 0, 0, 0ull};
#pragma unroll
  for (int half = 0; half < 2; ++half) {
    unsigned mm[2][5][6];
#pragma unroll
    for (int ch = 0; ch < 2; ++ch)
#pragma unroll
      for (int r = 0; r < 5; ++r)
#pragma unroll
        for (int c = 0; c < 6; ++c) {
          const int yr = y - 2 + r, xc = x - 2 + c;
          const bool ok = ((unsigned)yr < 64u) & ((unsigned)xc < 64u);
          mm[ch][r][c] = ok ?
            im32[2 * ((size_t)(b * 2 + ch) * 4096 + yr * 64 + xc) + half] : 0u;
        }
    k2_half(mm, w, half * 32, A0, B0, A1, B1, st0, st1);
  }
  unsigned long long* sp = s1 + (size_t)(b * 8 + o) * 4096;
  sp[y * 64 + x]     = st0.hist;
  sp[y * 64 + x + 1] = st1.hist;
}

// ---- K3: spike2 = spike(deconv2x2(psp2(s1))), both o per thread ----
__device__ __forceinline__ void k3_half(const unsigned (&mm)[8],
    const double (&wA)[8], const double (&wB)[8], int tbase,
    double& A0, double& B0, double& A1, double& B1, Spike& st0, Spike& st1) {
  for (int tt = 0; tt < 32; ++tt) {
    const int t = tbase + tt;
    double d0 = 0.0, d1 = 0.0;
#pragma unroll
    for (int c = 0; c < 8; ++c) {
      const double bb = bitd(mm[c], tt);
      d0 = fma(wA[c], bb, d0);
      d1 = fma(wB[c], bb, d1);
    }
    B0 = D_TAU2 * (B0 + A0); A0 = D_TAU2 * A0 + d0;
    B1 = D_TAU2 * (B1 + A1); A1 = D_TAU2 * A1 + d1;
    (void)spike_step(st0, B0, t, 50.0, DR2, D32_2, CR2);
    (void)spike_step(st1, B1, t, 50.0, DR2, D32_2, CR2);
  }
}

__global__ __launch_bounds__(256) void k_deconv_spike(
    const unsigned long long* __restrict__ s1, const float* __restrict__ w2f,
    unsigned long long* __restrict__ s2) {
  const int X = threadIdx.x;                       // 0..127
  const int Y = blockIdx.x * 2 + threadIdx.y;      // 0..127
  const int b = blockIdx.z;                        // 0..7
  const int xi = X >> 1, jj = X & 1, yi = Y >> 1, ii = Y & 1;
  double wA[8], wB[8];
#pragma unroll
  for (int c = 0; c < 8; ++c) {
    wA[c] = (double)w2f[((c * 2 + 0) * 2 + ii) * 2 + jj] * C_TAU2;
    wB[c] = (double)w2f[((c * 2 + 1) * 2 + ii) * 2 + jj] * C_TAU2;
  }
  const unsigned* s132 = (const unsigned*)s1;
  double A0 = 0.0, B0 = 0.0, A1 = 0.0, B1 = 0.0;
  Spike st0 = {0, 0, 0, 0, 0ull}, st1 = {0, 0, 0, 0, 0ull};
#pragma unroll
  for (int half = 0; half < 2; ++half) {
    unsigned mm[8];
#pragma unroll
    for (int c = 0; c < 8; ++c)
      mm[c] = s132[2 * ((size_t)(b * 8 + c) * 4096 + yi * 64 + xi) + half];
    k3_half(mm, wA, wB, half * 32, A0, B0, A1, B1, st0, st1);
  }
  s2[(size_t)(b * 2 + 0) * 16384 + Y * 128 + X] = st0.hist;
  s2[(size_t)(b * 2 + 1) * 16384 + Y * 128 + X] = st1.hist;
}

// ---- K4: out = spike(conv3x3(psp3(s2)) + psp1(bilinear(input))) ----
__device__ __forceinline__ void k4_half(const unsigned (&mc)[18],
    const unsigned (&ms0)[4], const unsigned (&ms1)[4],
    const double (&wA)[18], const double (&wB)[18], const double (&ws)[4],
    int tbase, double& Ac0, double& Bc0, double& Ac1, double& Bc1,
    double& As0, double& Bs0, double& As1, double& Bs1,
    Spike& st0, Spike& st1) {
  for (int tt = 0; tt < 32; ++tt) {
    const int t = tbase + tt;
    double d0 = 0.0, d1 = 0.0, e0 = 0.0, e1 = 0.0;
#pragma unroll
    for (int i = 0; i < 18; ++i) {
      const double bb = bitd(mc[i], tt);
      d0 = fma(wA[i], bb, d0);
      d1 = fma(wB[i], bb, d1);
    }
#pragma unroll
    for (int i = 0; i < 4; ++i) {
      e0 = fma(ws[i], bitd(ms0[i], tt), e0);
      e1 = fma(ws[i], bitd(ms1[i], tt), e1);
    }
    Bc0 = D_TAU4 * (Bc0 + Ac0); Ac0 = D_TAU4 * Ac0 + d0;
    Bc1 = D_TAU4 * (Bc1 + Ac1); Ac1 = D_TAU4 * Ac1 + d1;
    Bs0 = D_TAU1 * (Bs0 + As0); As0 = D_TAU1 * As0 + e0;
    Bs1 = D_TAU1 * (Bs1 + As1); As1 = D_TAU1 * As1 + e1;
    (void)spike_step(st0, Bc0 + Bs0, t, 100.0, DR3, D32_3, CR3);
    (void)spike_step(st1, Bc1 + Bs1, t, 100.0, DR3, D32_3, CR3);
  }
}

__global__ __launch_bounds__(256) void k_conv3_spike_out(
    const unsigned long long* __restrict__ s2, const float* __restrict__ w3f,
    const unsigned long long* __restrict__ im, float* __restrict__ out) {
  const int X = threadIdx.x;                       // 0..127
  const int Y = blockIdx.x * 2 + threadIdx.y;      // 0..127
  const int b = blockIdx.z;                        // 0..7
  double wA[18], wB[18];
#pragma unroll
  for (int i = 0; i < 18; ++i) {
    wA[i] = (double)w3f[i]      * C_TAU4;
    wB[i] = (double)w3f[18 + i] * C_TAU4;
  }
  // bilinear 2x taps (half-pixel, clamped), C_TAU1 folded in
  const int y0 = (Y - 1) >> 1;
  const int x0 = (X - 1) >> 1;
  const double wy1 = (Y & 1) ? 0.25 : 0.75, wy0 = 1.0 - wy1;
  const double wx1 = (X & 1) ? 0.25 : 0.75, wx0 = 1.0 - wx1;
  const int iy0 = max(y0, 0), iy1 = min(y0 + 1, 63);
  const int ix0 = max(x0, 0), ix1 = min(x0 + 1, 63);
  double ws[4];
  ws[0] = wy0 * wx0 * C_TAU1; ws[1] = wy0 * wx1 * C_TAU1;
  ws[2] = wy1 * wx0 * C_TAU1; ws[3] = wy1 * wx1 * C_TAU1;
  const size_t skidx[4] = {
    (size_t)iy0 * 64 + ix0, (size_t)iy0 * 64 + ix1,
    (size_t)iy1 * 64 + ix0, (size_t)iy1 * 64 + ix1 };
  const unsigned* s232 = (const unsigned*)s2;
  const unsigned* im32 = (const unsigned*)im;
  double Ac0 = 0, Bc0 = 0, Ac1 = 0, Bc1 = 0;
  double As0 = 0, Bs0 = 0, As1 = 0, Bs1 = 0;
  Spike st0 = {0, 0, 0, 0, 0ull}, st1 = {0, 0, 0, 0, 0ull};
#pragma unroll
  for (int half = 0; half < 2; ++half) {
    unsigned mc[18], ms0[4], ms1[4];
#pragma unroll
    for (int cc = 0; cc < 2; ++cc)
#pragma unroll
      for (int ky = 0; ky < 3; ++ky)
#pragma unroll
        for (int kx = 0; kx < 3; ++kx) {
          const int yn = Y - 1 + ky, xn = X - 1 + kx;
          const bool ok = ((unsigned)yn < 128u) & ((unsigned)xn < 128u);
          mc[cc * 9 + ky * 3 + kx] = ok ?
            s232[2 * ((size_t)(b * 2 + cc) * 16384 + yn * 128 + xn) + half] : 0u;
        }
#pragma unroll
    for (int i = 0; i < 4; ++i) {
      ms0[i] = im32[2 * ((size_t)(b * 2 + 0) * 4096 + skidx[i]) + half];
      ms1[i] = im32[2 * ((size_t)(b * 2 + 1) * 4096 + skidx[i]) + half];
    }
    k4_half(mc, ms0, ms1, wA, wB, ws, half * 32,
            Ac0, Bc0, Ac1, Bc1, As0, Bs0, As1, Bs1, st0, st1);
  }
#pragma unroll
  for (int o = 0; o < 2; ++o) {
    const unsigned long long h = o ? st1.hist : st0.hist;
    float* op = out + (((size_t)(b * 2 + o) * 128 + Y) * 128 + X) * 64;
#pragma unroll
    for (int t4 = 0; t4 < 16; ++t4) {
      float4 v;
      v.x = ((h >> (t4 * 4 + 0)) & 1ull) ? 1.0f : 0.0f;
      v.y = ((h >> (t4 * 4 + 1)) & 1ull) ? 1.0f : 0.0f;
      v.z = ((h >> (t4 * 4 + 2)) & 1ull) ? 1.0f : 0.0f;
      v.w = ((h >> (t4 * 4 + 3)) & 1ull) ? 1.0f : 0.0f;
      reinterpret_cast<float4*>(op)[t4] = v;
    }
  }
}

extern "C" void kernel_launch(void* const* d_in, const int* in_sizes, int n_in,
                              void* d_out, int out_size, void* d_ws, size_t ws_size,
                              hipStream_t stream) {
  const float* spikeIn = (const float*)d_in[0];   // (8,2,64,64,64) fp32
  const float* w1 = (const float*)d_in[1];        // (8,2,5,5)
  const float* w2 = (const float*)d_in[2];        // (8,2,2,2) = (in,out,i,j)
  const float* w3 = (const float*)d_in[3];        // (2,2,3,3)
  float* out = (float*)d_out;                     // (8,2,128,128,64) fp32

  unsigned long long* IM = (unsigned long long*)d_ws;   // 0.5 MB
  unsigned long long* S1 = IM + (size_t)16 * 4096;      // 2 MB
  unsigned long long* S2 = S1 + (size_t)64 * 4096;      // 2 MB

  k_masks<<<dim3(256), dim3(256), 0, stream>>>(spikeIn, IM);
  k_conv1_spike<<<dim3(8, 8, 8), dim3(256), 0, stream>>>(IM, w1, S1);
  k_deconv_spike<<<dim3(64, 1, 8), dim3(128, 2), 0, stream>>>(S1, w2, S2);
  k_conv3_spike_out<<<dim3(64, 1, 8), dim3(128, 2), 0, stream>>>(S2, w3, IM, out);
}